// Round 12
// baseline (430.125 us; speedup 1.0000x reference)
//
#include <hip/hip_runtime.h>
#include <hip/hip_bf16.h>

// Shapes (fixed by the problem)
#define VV 50000
#define EE 128
#define HH 128
#define OO 128
#define BB 64
#define TT 512

typedef __bf16 bf16_t;
typedef __attribute__((ext_vector_type(8))) __bf16 bf16x8;
typedef __attribute__((ext_vector_type(4))) __bf16 bf16x4;
typedef __attribute__((ext_vector_type(4))) float floatx4;

__device__ __forceinline__ bf16x8 ldb8(const bf16_t* p) {
    return *reinterpret_cast<const bf16x8*>(p);
}

// load 8 consecutive fp32, round to bf16 fragment (two float4 loads)
__device__ __forceinline__ bf16x8 ldf8_bf(const float* p) {
    const float4* q = reinterpret_cast<const float4*>(p);
    float4 u = q[0], v = q[1];
    bf16x8 r;
    r[0] = (__bf16)u.x; r[1] = (__bf16)u.y; r[2] = (__bf16)u.z; r[3] = (__bf16)u.w;
    r[4] = (__bf16)v.x; r[5] = (__bf16)v.y; r[6] = (__bf16)v.z; r[7] = (__bf16)v.w;
    return r;
}

__device__ __forceinline__ float fast_rcp(float x) { return __builtin_amdgcn_rcpf(x); }
__device__ __forceinline__ float sigmoid_f(float x) {
    return fast_rcp(1.0f + __expf(-x));
}
__device__ __forceinline__ float tanh_f(float x) {
    float e = __expf(2.0f * x);
    return 1.0f - 2.0f * fast_rcp(e + 1.0f);
}

// LDS-only barrier: wait LDS ops, sync — do NOT drain vmcnt (hist stores and
// gx ring-prefetch loads stay in flight across steps).
__device__ __forceinline__ void lds_barrier() {
    asm volatile("s_waitcnt lgkmcnt(0)\n\ts_barrier" ::: "memory");
}

// -------- K0: preconvert small weights fp32->bf16 + fold gx bias.
__global__ __launch_bounds__(256) void k0_conv(
    const float* __restrict__ we,
    const float* __restrict__ wihf, const float* __restrict__ wihb,
    const float* __restrict__ whhf, const float* __restrict__ whhb,
    const float* __restrict__ wh2o,
    const float* __restrict__ bihf, const float* __restrict__ bhhf,
    const float* __restrict__ bihb, const float* __restrict__ bhhb,
    bf16_t* __restrict__ we_bf,
    bf16_t* __restrict__ wih_bf, bf16_t* __restrict__ whh_bf,
    bf16_t* __restrict__ wh2o_bf, float* __restrict__ gxbias) {
    int tid = blockIdx.x * 256 + threadIdx.x;
    int np = gridDim.x * 256;
    for (int i = tid; i < HH * EE; i += np) we_bf[i] = (bf16_t)we[i];
    for (int i = tid; i < 384 * HH; i += np) {
        wih_bf[i] = (bf16_t)wihf[i];
        wih_bf[384 * HH + i] = (bf16_t)wihb[i];
        whh_bf[i] = (bf16_t)whhf[i];
        whh_bf[384 * HH + i] = (bf16_t)whhb[i];
    }
    for (int i = tid; i < OO * 256; i += np) wh2o_bf[i] = (bf16_t)wh2o[i];
    if (tid < 768) {
        int dir = tid / 384, n = tid % 384;
        const float* bih = dir ? bihb : bihf;
        const float* bhh = dir ? bhhb : bhhf;
        gxbias[tid] = bih[n] + (n < 256 ? bhh[n] : 0.0f);  // bhh_n goes in K3's C-init
    }
}

// -------- K12 (fused K1+K2), 4 timesteps per block, with dead-time skip:
// lens sorted descending -> tile g's max len = lens[16g]; blocks entirely past
// it produce gx no one reads (K3 stops at its group Lmax <= lens[16g]).
__global__ __launch_bounds__(256) void k12_gx(const int* __restrict__ X,
                                              const float* __restrict__ emb,
                                              const bf16_t* __restrict__ we_bf,
                                              const float* __restrict__ be,
                                              const bf16_t* __restrict__ wih_bf,
                                              const float* __restrict__ gxbias,
                                              const int* __restrict__ lens,
                                              bf16_t* __restrict__ gx3) {
    int blk = blockIdx.x;            // 0..511 = tq*4 + g
    int tq = blk >> 2;
    int g = blk & 3;                 // 16-sample tile
    if (4 * tq >= lens[16 * g]) return;   // uniform: whole block dead

    int lane = threadIdx.x & 63;
    int w2 = threadIdx.x >> 6;       // wave 0..3
    int quad = lane >> 4, col = lane & 15;

    __shared__ bf16_t xs[4][16 * 136];   // 4 xh tiles, row-padded

    // stage 1 x4: xh = emb[X] @ We^T + be (A rows = 16 samples at t=4tq+tt)
#pragma unroll
    for (int tt = 0; tt < 4; ++tt) {
        int t = 4 * tq + tt;
        int v = X[(g * 16 + col) * TT + t];
        bf16x8 a[4];
#pragma unroll
        for (int kc = 0; kc < 4; ++kc)
            a[kc] = ldf8_bf(emb + (size_t)v * EE + kc * 32 + quad * 8);
#pragma unroll
        for (int tl = 0; tl < 2; ++tl) {
            int n = 32 * w2 + 16 * tl + col;
            floatx4 acc = {0.f, 0.f, 0.f, 0.f};
#pragma unroll
            for (int kc = 0; kc < 4; ++kc) {
                bf16x8 bw = ldb8(we_bf + (size_t)n * EE + kc * 32 + quad * 8);
                acc = __builtin_amdgcn_mfma_f32_16x16x32_bf16(a[kc], bw, acc, 0, 0, 0);
            }
            float bias = be[n];
#pragma unroll
            for (int r = 0; r < 4; ++r)
                xs[tt][(quad * 4 + r) * 136 + n] = (bf16_t)(acc[r] + bias);
        }
    }
    __syncthreads();

    // stage 2: gx = xh @ Wih^T + gxbias, both dirs; Wih loaded once per n-tile
    bf16x8 a2[4][4];
#pragma unroll
    for (int tt = 0; tt < 4; ++tt)
#pragma unroll
        for (int kc = 0; kc < 4; ++kc)
            a2[tt][kc] = ldb8(xs[tt] + col * 136 + kc * 32 + quad * 8);

#pragma unroll
    for (int tl = 0; tl < 12; ++tl) {
        int idx = w2 * 12 + tl;          // 0..47
        int dir = idx >= 24;
        int n = (idx - dir * 24) * 16 + col;   // 0..383
        bf16x8 bw[4];
#pragma unroll
        for (int kc = 0; kc < 4; ++kc)
            bw[kc] = ldb8(wih_bf + ((size_t)dir * 384 + n) * HH + kc * 32 + quad * 8);
        float bias = gxbias[dir * 384 + n];
#pragma unroll
        for (int tt = 0; tt < 4; ++tt) {
            int t = 4 * tq + tt;
            floatx4 acc = {0.f, 0.f, 0.f, 0.f};
#pragma unroll
            for (int kc = 0; kc < 4; ++kc)
                acc = __builtin_amdgcn_mfma_f32_16x16x32_bf16(a2[tt][kc], bw[kc], acc, 0, 0, 0);
            bf16x4 pack;
#pragma unroll
            for (int r = 0; r < 4; ++r)
                pack[r] = (__bf16)(acc[r] + bias);   // D row r -> sample 16g+quad*4+r
            *reinterpret_cast<bf16x4*>(
                gx3 + (((size_t)(dir * 16 + 4 * g + quad) * TT + t) * 384 + n) * 4) = pack;
        }
    }
}

// -------- K3: masked GRU recurrence (R9 structure — converged at ~204 us).
// grid (16 groups of 4 samples, 2 dirs) = 32 blocks, 512 threads = 8 waves.
// Wall = 512 steps x ~956 cyc: LDS-pipe serialization of 8 waves' A-operand
// traffic (~384 cyc, irreducible register-content flow) + serial chain
// (barrier -> ds_read -> MFMA -> transcendental gates -> h write, ~570).
// Measured-worse alternatives: 4 waves (R7, 1580 cyc/step), dir-fusion (R10,
// 1720 cyc/2-dir-step), swizzle fold (R6/R8).
#define HPAD 144
#define HBUF (4 * HPAD)
__global__ __launch_bounds__(512) void k3_gru(const bf16_t* __restrict__ gx3,
                                              const bf16_t* __restrict__ whh_bf,
                                              const float* __restrict__ bhh_f,
                                              const float* __restrict__ bhh_b,
                                              const int* __restrict__ lens,
                                              bf16_t* __restrict__ hist2) {
    int g16 = blockIdx.x;    // 4-sample group: samples 4*g16 .. 4*g16+3
    int dir = blockIdx.y;
    const float* bhh = dir ? bhh_b : bhh_f;

    int tid = threadIdx.x;
    int w = tid >> 6;        // wave 0..7
    int lane = tid & 63;
    int quad = lane >> 4, col = lane & 15;
    int j = 16 * w + col;    // owned hidden column

    __shared__ bf16_t hl[2 * HBUF];   // double-buffered h, 4 rows (samples)
    for (int i = tid; i < 2 * HBUF; i += 512) hl[i] = (bf16_t)0.f;

    int len1 = lens[4 * g16 + quad];      // this lane's sample
    int Lmax = max(max(lens[4 * g16], lens[4 * g16 + 1]),
                   max(lens[4 * g16 + 2], lens[4 * g16 + 3]));

    float bhn = bhh[256 + j];

    // Whh B-fragments (pre-converted bf16), resident for all steps
    bf16x8 Bw[3][4];
#pragma unroll
    for (int gate = 0; gate < 3; ++gate)
#pragma unroll
        for (int kc = 0; kc < 4; ++kc)
            Bw[gate][kc] = ldb8(whh_bf + ((size_t)dir * 384 + gate * 128 + j) * HH + kc * 32 + quad * 8);

    const bf16_t* gbase = gx3 + (size_t)(dir * 16 + g16) * TT * 1536;
    bf16_t* hb = hist2 + (size_t)(dir * 16 + g16) * TT * 512;
    int loff[3];
#pragma unroll
    for (int gate = 0; gate < 3; ++gate)
        loff[gate] = (gate * 128 + j) * 4 + quad;
    int hoff = quad * 128 + j;
    int aoff = (col & 3) * HPAD + quad * 8;   // broadcast A-read offset

    float h = 0.f;
    int S4 = (Lmax + 3) & ~3;
    bool lowquad = (quad & 1) == 0;
    bool lowhalf = (quad & 2) == 0;

    // prefetch ring, depth 4 (raw bf16 scalars; convert at consumption)
    __bf16 ring[4][3];
#pragma unroll
    for (int u = 0; u < 4; ++u) {
        int tr = dir ? (Lmax - 1 - u) : u;
        int t = min(max(tr, 0), Lmax - 1);
#pragma unroll
        for (int gate = 0; gate < 3; ++gate)
            ring[u][gate] = gbase[(size_t)t * 1536 + loff[gate]];
    }
    lds_barrier();   // zero-init visible

    for (int sb = 0; sb < S4; sb += 4) {
#pragma unroll
        for (int u = 0; u < 4; ++u) {
            int s = sb + u;
            int tr = dir ? (Lmax - 1 - s) : s;
            int t = min(max(tr, 0), Lmax - 1);     // clamped for tail steps
            const bf16_t* hc = hl + (s & 1) * HBUF;
            bf16_t* hn = hl + ((s + 1) & 1) * HBUF;

            // consume ring slot u (loads issued 4 steps ago)
            float gx0 = (float)ring[u][0];
            float gx1 = (float)ring[u][1];
            float gx2 = (float)ring[u][2];

            // A fragments from LDS h (broadcast rows: sample = row & 3)
            bf16x8 a[4];
#pragma unroll
            for (int kc = 0; kc < 4; ++kc)
                a[kc] = ldb8(hc + aoff + kc * 32);

            // 3 chains; bhn folded into n-gate C-init
            floatx4 cr = {0.f, 0.f, 0.f, 0.f};
            floatx4 cz = {0.f, 0.f, 0.f, 0.f};
            floatx4 cn = {bhn, bhn, bhn, bhn};
#pragma unroll
            for (int kc = 0; kc < 4; ++kc) {
                cr = __builtin_amdgcn_mfma_f32_16x16x32_bf16(a[kc], Bw[0][kc], cr, 0, 0, 0);
                cz = __builtin_amdgcn_mfma_f32_16x16x32_bf16(a[kc], Bw[1][kc], cz, 0, 0, 0);
                cn = __builtin_amdgcn_mfma_f32_16x16x32_bf16(a[kc], Bw[2][kc], cn, 0, 0, 0);
            }

            // refill ring slot u for step s+4
            {
                int sn = s + 4;
                int trn = dir ? (Lmax - 1 - sn) : sn;
                int tn = min(max(trn, 0), Lmax - 1);
#pragma unroll
                for (int gate = 0; gate < 3; ++gate)
                    ring[u][gate] = gbase[(size_t)tn * 1536 + loff[gate]];
            }

            // register select: reg r = gates of sample r (D-row periodicity);
            // this lane's sample is quad -> pick reg[quad]. No cross-lane ops.
            float aR = lowhalf ? (lowquad ? cr[0] : cr[1]) : (lowquad ? cr[2] : cr[3]);
            float aZ = lowhalf ? (lowquad ? cz[0] : cz[1]) : (lowquad ? cz[2] : cz[3]);
            float aN = lowhalf ? (lowquad ? cn[0] : cn[1]) : (lowquad ? cn[2] : cn[3]);

            // gate math: ONE channel (sample=quad, hidden=j) per lane
            float rg = sigmoid_f(aR + gx0);
            float zg = sigmoid_f(aZ + gx1);
            float ng = tanh_f(gx2 + rg * aN);
            float hnew = ng + zg * (h - ng);
            bool upd = (s < Lmax) && (t < len1);
            h = upd ? hnew : h;
            bf16_t h16 = (bf16_t)h;
            hn[quad * HPAD + j] = h16;            // LDS row = sample
            hb[(size_t)t * 512 + hoff] = h16;     // hist2 per-block region

            lds_barrier();   // new h visible; old buffer free
        }
    }
}

// -------- K45 (fused K4+K5), 512 threads: one block per sample. Per 16-t
// chunk (t < len only): scores via MFMA with M-dim = time (8 waves x 1 n-tile,
// K=256 over h_f||h_b, N=128), then in-block softmax + pooled with 2-way
// t-split. hist2 rows at t>=len are stale/poison but FINITE and masked.
__global__ __launch_bounds__(512) void k45_pool(const bf16_t* __restrict__ hist2,
                                                const bf16_t* __restrict__ wh2o_bf,
                                                const float* __restrict__ bh2o,
                                                const float* __restrict__ uw,
                                                const int* __restrict__ lens,
                                                float* __restrict__ out) {
    int b = blockIdx.x;
    int g16 = b >> 2, bl = b & 3;
    int tid = threadIdx.x;
    int lane = tid & 63, w = tid >> 6;        // 8 waves
    int quad = lane >> 4, col = lane & 15;
    int len = lens[b];

    __shared__ float smax[TT][8];   // per-wave partial scores, 16 KB
    __shared__ float alpha[TT];
    __shared__ float red[512];

    const bf16_t* hf = hist2 + (size_t)g16 * TT * 512 + bl * 128;        // fwd
    const bf16_t* hbk = hist2 + (size_t)(16 + g16) * TT * 512 + bl * 128; // bwd

    // this wave's n-tile (N=128 over 8 waves)
    int n0 = w * 16 + col;
    float bias0 = bh2o[n0], u0 = uw[n0];

    int nch = (len + 15) >> 4;
    for (int ch = 0; ch < nch; ++ch) {
        int t0 = ch * 16;
        int t = t0 + col;                 // A row m = t offset (t <= 511)
        bf16x8 a[8];
#pragma unroll
        for (int kc = 0; kc < 4; ++kc) {
            a[kc]     = ldb8(hf  + (size_t)t * 512 + kc * 32 + quad * 8);
            a[kc + 4] = ldb8(hbk + (size_t)t * 512 + kc * 32 + quad * 8);
        }
        floatx4 acc = {0.f, 0.f, 0.f, 0.f};
#pragma unroll
        for (int kc = 0; kc < 8; ++kc) {
            bf16x8 bw = ldb8(wh2o_bf + (size_t)n0 * 256 + kc * 32 + quad * 8);
            acc = __builtin_amdgcn_mfma_f32_16x16x32_bf16(a[kc], bw, acc, 0, 0, 0);
        }
        float p4[4];
#pragma unroll
        for (int r = 0; r < 4; ++r)
            p4[r] = tanh_f(acc[r] + bias0) * u0;
        // reduce over the 16 cols of this quad group (D rows = t's)
#pragma unroll
        for (int m = 1; m < 16; m <<= 1)
#pragma unroll
            for (int r = 0; r < 4; ++r)
                p4[r] += __shfl_xor(p4[r], m, 64);
        if (col == 0) {
#pragma unroll
            for (int r = 0; r < 4; ++r)
                smax[t0 + quad * 4 + r][w] = p4[r];
        }
    }
    __syncthreads();

    // softmax over valid t
    float mx = -1e30f;
    for (int t = tid; t < TT; t += 512) {
        float s = -1e30f;
        if (t < len)
            s = (smax[t][0] + smax[t][1]) + (smax[t][2] + smax[t][3]) +
                (smax[t][4] + smax[t][5]) + (smax[t][6] + smax[t][7]);
        alpha[t] = s;
        mx = fmaxf(mx, s);
    }
    red[tid] = mx;
    __syncthreads();
    for (int s = 256; s > 0; s >>= 1) {
        if (tid < s) red[tid] = fmaxf(red[tid], red[tid + s]);
        __syncthreads();
    }
    mx = red[0];
    __syncthreads();
    float sum = 0.f;
    for (int t = tid; t < TT; t += 512) {
        float e = (t < len) ? __expf(alpha[t] - mx) : 0.f;
        alpha[t] = e;
        sum += e;
    }
    red[tid] = sum;
    __syncthreads();
    for (int s = 256; s > 0; s >>= 1) {
        if (tid < s) red[tid] += red[tid + s];
        __syncthreads();
    }
    float inv = fast_rcp(red[0]);
    __syncthreads();

    // pooled: 512 threads = 2 t-halves x 256 channels
    int c = tid & 255;
    int half = tid >> 8;
    int dir = c >> 7;
    int j = c & 127;
    const bf16_t* hbase = (dir ? hbk : hf) + j;
    float acc = 0.f;
    for (int t = half; t < len; t += 2)
        acc += alpha[t] * (float)hbase[(size_t)t * 512];
    red[tid] = acc;
    __syncthreads();
    if (tid < 256)
        out[(size_t)b * 256 + tid] = (red[tid] + red[tid + 256]) * inv;
}

extern "C" void kernel_launch(void* const* d_in, const int* in_sizes, int n_in,
                              void* d_out, int out_size, void* d_ws, size_t ws_size,
                              hipStream_t stream) {
    const int* X       = (const int*)d_in[0];
    const int* lens    = (const int*)d_in[1];
    const float* emb   = (const float*)d_in[3];
    const float* We2i  = (const float*)d_in[4];
    const float* be2i  = (const float*)d_in[5];
    const float* Wihf  = (const float*)d_in[6];
    const float* Whhf  = (const float*)d_in[7];
    const float* bihf  = (const float*)d_in[8];
    const float* bhhf  = (const float*)d_in[9];
    const float* Wihb  = (const float*)d_in[10];
    const float* Whhb  = (const float*)d_in[11];
    const float* bihb  = (const float*)d_in[12];
    const float* bhhb  = (const float*)d_in[13];
    const float* Wh2o  = (const float*)d_in[14];
    const float* bh2o  = (const float*)d_in[15];
    const float* uw    = (const float*)d_in[16];

    char* ws = (char*)d_ws;
    size_t off = 0;
    bf16_t* we_bf = (bf16_t*)(ws + off);   off += (size_t)HH * EE * 2;          // 32 KB
    bf16_t* wih_bf = (bf16_t*)(ws + off);  off += (size_t)2 * 384 * HH * 2;     // 192 KB
    bf16_t* whh_bf = (bf16_t*)(ws + off);  off += (size_t)2 * 384 * HH * 2;     // 192 KB
    bf16_t* wh2o_bf = (bf16_t*)(ws + off); off += (size_t)OO * 256 * 2;         // 64 KB
    float* gxbias = (float*)(ws + off);    off += 768 * 4;                      // 3 KB
    off = (off + 255) & ~(size_t)255;
    bf16_t* gx3 = (bf16_t*)(ws + off);     off += (size_t)32 * TT * 384 * 4 * 2; // 50.3 MB
    bf16_t* hist2 = (bf16_t*)(ws + off);   off += (size_t)32 * TT * 4 * 128 * 2; // 16.8 MB

    float* out = (float*)d_out;

    k0_conv<<<dim3(256), dim3(256), 0, stream>>>(We2i, Wihf, Wihb, Whhf, Whhb,
                                                 Wh2o, bihf, bhhf, bihb, bhhb,
                                                 we_bf, wih_bf, whh_bf, wh2o_bf, gxbias);
    k12_gx<<<dim3(TT), dim3(256), 0, stream>>>(X, emb, we_bf, be2i, wih_bf, gxbias, lens, gx3);
    k3_gru<<<dim3(16, 2), dim3(512), 0, stream>>>(gx3, whh_bf, bhhf, bhhb, lens, hist2);
    k45_pool<<<dim3(BB), dim3(512), 0, stream>>>(hist2, wh2o_bf, bh2o, uw, lens, out);
}

// Round 13
// 396.029 us; speedup vs baseline: 1.0861x; 1.0861x over previous
//
#include <hip/hip_runtime.h>
#include <hip/hip_bf16.h>

// Shapes (fixed by the problem)
#define VV 50000
#define EE 128
#define HH 128
#define OO 128
#define BB 64
#define TT 512

typedef __bf16 bf16_t;
typedef __attribute__((ext_vector_type(8))) __bf16 bf16x8;
typedef __attribute__((ext_vector_type(4))) __bf16 bf16x4;
typedef __attribute__((ext_vector_type(4))) float floatx4;

__device__ __forceinline__ bf16x8 ldb8(const bf16_t* p) {
    return *reinterpret_cast<const bf16x8*>(p);
}

// load 8 consecutive fp32, round to bf16 fragment (two float4 loads)
__device__ __forceinline__ bf16x8 ldf8_bf(const float* p) {
    const float4* q = reinterpret_cast<const float4*>(p);
    float4 u = q[0], v = q[1];
    bf16x8 r;
    r[0] = (__bf16)u.x; r[1] = (__bf16)u.y; r[2] = (__bf16)u.z; r[3] = (__bf16)u.w;
    r[4] = (__bf16)v.x; r[5] = (__bf16)v.y; r[6] = (__bf16)v.z; r[7] = (__bf16)v.w;
    return r;
}

__device__ __forceinline__ float fast_rcp(float x) { return __builtin_amdgcn_rcpf(x); }
__device__ __forceinline__ float sigmoid_f(float x) {
    return fast_rcp(1.0f + __expf(-x));
}
__device__ __forceinline__ float tanh_f(float x) {
    float e = __expf(2.0f * x);
    return 1.0f - 2.0f * fast_rcp(e + 1.0f);
}

// LDS-only barrier: wait LDS ops, sync — do NOT drain vmcnt (hist stores and
// gx ring-prefetch loads stay in flight across steps).
__device__ __forceinline__ void lds_barrier() {
    asm volatile("s_waitcnt lgkmcnt(0)\n\ts_barrier" ::: "memory");
}

// -------- K0: preconvert small weights fp32->bf16 + fold gx bias.
__global__ __launch_bounds__(256) void k0_conv(
    const float* __restrict__ we,
    const float* __restrict__ wihf, const float* __restrict__ wihb,
    const float* __restrict__ whhf, const float* __restrict__ whhb,
    const float* __restrict__ wh2o,
    const float* __restrict__ bihf, const float* __restrict__ bhhf,
    const float* __restrict__ bihb, const float* __restrict__ bhhb,
    bf16_t* __restrict__ we_bf,
    bf16_t* __restrict__ wih_bf, bf16_t* __restrict__ whh_bf,
    bf16_t* __restrict__ wh2o_bf, float* __restrict__ gxbias) {
    int tid = blockIdx.x * 256 + threadIdx.x;
    int np = gridDim.x * 256;
    for (int i = tid; i < HH * EE; i += np) we_bf[i] = (bf16_t)we[i];
    for (int i = tid; i < 384 * HH; i += np) {
        wih_bf[i] = (bf16_t)wihf[i];
        wih_bf[384 * HH + i] = (bf16_t)wihb[i];
        whh_bf[i] = (bf16_t)whhf[i];
        whh_bf[384 * HH + i] = (bf16_t)whhb[i];
    }
    for (int i = tid; i < OO * 256; i += np) wh2o_bf[i] = (bf16_t)wh2o[i];
    if (tid < 768) {
        int dir = tid / 384, n = tid % 384;
        const float* bih = dir ? bihb : bihf;
        const float* bhh = dir ? bhhb : bhhf;
        gxbias[tid] = bih[n] + (n < 256 ? bhh[n] : 0.0f);  // bhh_n goes in K3's C-init
    }
}

// -------- K12 (fused K1+K2), 4 timesteps per block, with dead-time skip:
// lens sorted descending -> tile g's max len = lens[16g]; blocks entirely past
// it produce gx no one reads (K3 stops at its group Lmax <= lens[16g]).
__global__ __launch_bounds__(256) void k12_gx(const int* __restrict__ X,
                                              const float* __restrict__ emb,
                                              const bf16_t* __restrict__ we_bf,
                                              const float* __restrict__ be,
                                              const bf16_t* __restrict__ wih_bf,
                                              const float* __restrict__ gxbias,
                                              const int* __restrict__ lens,
                                              bf16_t* __restrict__ gx3) {
    int blk = blockIdx.x;            // 0..511 = tq*4 + g
    int tq = blk >> 2;
    int g = blk & 3;                 // 16-sample tile
    if (4 * tq >= lens[16 * g]) return;   // uniform: whole block dead

    int lane = threadIdx.x & 63;
    int w2 = threadIdx.x >> 6;       // wave 0..3
    int quad = lane >> 4, col = lane & 15;

    __shared__ bf16_t xs[4][16 * 136];   // 4 xh tiles, row-padded

    // stage 1 x4: xh = emb[X] @ We^T + be (A rows = 16 samples at t=4tq+tt)
#pragma unroll
    for (int tt = 0; tt < 4; ++tt) {
        int t = 4 * tq + tt;
        int v = X[(g * 16 + col) * TT + t];
        bf16x8 a[4];
#pragma unroll
        for (int kc = 0; kc < 4; ++kc)
            a[kc] = ldf8_bf(emb + (size_t)v * EE + kc * 32 + quad * 8);
#pragma unroll
        for (int tl = 0; tl < 2; ++tl) {
            int n = 32 * w2 + 16 * tl + col;
            floatx4 acc = {0.f, 0.f, 0.f, 0.f};
#pragma unroll
            for (int kc = 0; kc < 4; ++kc) {
                bf16x8 bw = ldb8(we_bf + (size_t)n * EE + kc * 32 + quad * 8);
                acc = __builtin_amdgcn_mfma_f32_16x16x32_bf16(a[kc], bw, acc, 0, 0, 0);
            }
            float bias = be[n];
#pragma unroll
            for (int r = 0; r < 4; ++r)
                xs[tt][(quad * 4 + r) * 136 + n] = (bf16_t)(acc[r] + bias);
        }
    }
    __syncthreads();

    // stage 2: gx = xh @ Wih^T + gxbias, both dirs; Wih loaded once per n-tile
    bf16x8 a2[4][4];
#pragma unroll
    for (int tt = 0; tt < 4; ++tt)
#pragma unroll
        for (int kc = 0; kc < 4; ++kc)
            a2[tt][kc] = ldb8(xs[tt] + col * 136 + kc * 32 + quad * 8);

#pragma unroll
    for (int tl = 0; tl < 12; ++tl) {
        int idx = w2 * 12 + tl;          // 0..47
        int dir = idx >= 24;
        int n = (idx - dir * 24) * 16 + col;   // 0..383
        bf16x8 bw[4];
#pragma unroll
        for (int kc = 0; kc < 4; ++kc)
            bw[kc] = ldb8(wih_bf + ((size_t)dir * 384 + n) * HH + kc * 32 + quad * 8);
        float bias = gxbias[dir * 384 + n];
#pragma unroll
        for (int tt = 0; tt < 4; ++tt) {
            int t = 4 * tq + tt;
            floatx4 acc = {0.f, 0.f, 0.f, 0.f};
#pragma unroll
            for (int kc = 0; kc < 4; ++kc)
                acc = __builtin_amdgcn_mfma_f32_16x16x32_bf16(a2[tt][kc], bw[kc], acc, 0, 0, 0);
            bf16x4 pack;
#pragma unroll
            for (int r = 0; r < 4; ++r)
                pack[r] = (__bf16)(acc[r] + bias);   // D row r -> sample 16g+quad*4+r
            *reinterpret_cast<bf16x4*>(
                gx3 + (((size_t)(dir * 16 + 4 * g + quad) * TT + t) * 384 + n) * 4) = pack;
        }
    }
}

// -------- K3: masked GRU recurrence (R9 structure — converged at ~204 us).
// grid (16 groups of 4 samples, 2 dirs) = 32 blocks, 512 threads = 8 waves.
// Wall = 512 steps x ~956 cyc: LDS-pipe serialization of 8 waves' A-operand
// traffic (~384 cyc, irreducible register-content flow) + serial chain
// (barrier -> ds_read -> MFMA -> transcendental gates -> h write, ~570).
// Measured-worse alternatives: 4 waves (R7), dir-fusion (R10), swizzle folds
// (R6/R8), k45-widening (R12).
#define HPAD 144
#define HBUF (4 * HPAD)
__global__ __launch_bounds__(512) void k3_gru(const bf16_t* __restrict__ gx3,
                                              const bf16_t* __restrict__ whh_bf,
                                              const float* __restrict__ bhh_f,
                                              const float* __restrict__ bhh_b,
                                              const int* __restrict__ lens,
                                              bf16_t* __restrict__ hist2) {
    int g16 = blockIdx.x;    // 4-sample group: samples 4*g16 .. 4*g16+3
    int dir = blockIdx.y;
    const float* bhh = dir ? bhh_b : bhh_f;

    int tid = threadIdx.x;
    int w = tid >> 6;        // wave 0..7
    int lane = tid & 63;
    int quad = lane >> 4, col = lane & 15;
    int j = 16 * w + col;    // owned hidden column

    __shared__ bf16_t hl[2 * HBUF];   // double-buffered h, 4 rows (samples)
    for (int i = tid; i < 2 * HBUF; i += 512) hl[i] = (bf16_t)0.f;

    int len1 = lens[4 * g16 + quad];      // this lane's sample
    int Lmax = max(max(lens[4 * g16], lens[4 * g16 + 1]),
                   max(lens[4 * g16 + 2], lens[4 * g16 + 3]));

    float bhn = bhh[256 + j];

    // Whh B-fragments (pre-converted bf16), resident for all steps
    bf16x8 Bw[3][4];
#pragma unroll
    for (int gate = 0; gate < 3; ++gate)
#pragma unroll
        for (int kc = 0; kc < 4; ++kc)
            Bw[gate][kc] = ldb8(whh_bf + ((size_t)dir * 384 + gate * 128 + j) * HH + kc * 32 + quad * 8);

    const bf16_t* gbase = gx3 + (size_t)(dir * 16 + g16) * TT * 1536;
    bf16_t* hb = hist2 + (size_t)(dir * 16 + g16) * TT * 512;
    int loff[3];
#pragma unroll
    for (int gate = 0; gate < 3; ++gate)
        loff[gate] = (gate * 128 + j) * 4 + quad;
    int hoff = quad * 128 + j;
    int aoff = (col & 3) * HPAD + quad * 8;   // broadcast A-read offset

    float h = 0.f;
    int S4 = (Lmax + 3) & ~3;
    bool lowquad = (quad & 1) == 0;
    bool lowhalf = (quad & 2) == 0;

    // prefetch ring, depth 4 (raw bf16 scalars; convert at consumption)
    __bf16 ring[4][3];
#pragma unroll
    for (int u = 0; u < 4; ++u) {
        int tr = dir ? (Lmax - 1 - u) : u;
        int t = min(max(tr, 0), Lmax - 1);
#pragma unroll
        for (int gate = 0; gate < 3; ++gate)
            ring[u][gate] = gbase[(size_t)t * 1536 + loff[gate]];
    }
    lds_barrier();   // zero-init visible

    for (int sb = 0; sb < S4; sb += 4) {
#pragma unroll
        for (int u = 0; u < 4; ++u) {
            int s = sb + u;
            int tr = dir ? (Lmax - 1 - s) : s;
            int t = min(max(tr, 0), Lmax - 1);     // clamped for tail steps
            const bf16_t* hc = hl + (s & 1) * HBUF;
            bf16_t* hn = hl + ((s + 1) & 1) * HBUF;

            // consume ring slot u (loads issued 4 steps ago)
            float gx0 = (float)ring[u][0];
            float gx1 = (float)ring[u][1];
            float gx2 = (float)ring[u][2];

            // A fragments from LDS h (broadcast rows: sample = row & 3)
            bf16x8 a[4];
#pragma unroll
            for (int kc = 0; kc < 4; ++kc)
                a[kc] = ldb8(hc + aoff + kc * 32);

            // 3 chains; bhn folded into n-gate C-init
            floatx4 cr = {0.f, 0.f, 0.f, 0.f};
            floatx4 cz = {0.f, 0.f, 0.f, 0.f};
            floatx4 cn = {bhn, bhn, bhn, bhn};
#pragma unroll
            for (int kc = 0; kc < 4; ++kc) {
                cr = __builtin_amdgcn_mfma_f32_16x16x32_bf16(a[kc], Bw[0][kc], cr, 0, 0, 0);
                cz = __builtin_amdgcn_mfma_f32_16x16x32_bf16(a[kc], Bw[1][kc], cz, 0, 0, 0);
                cn = __builtin_amdgcn_mfma_f32_16x16x32_bf16(a[kc], Bw[2][kc], cn, 0, 0, 0);
            }

            // refill ring slot u for step s+4
            {
                int sn = s + 4;
                int trn = dir ? (Lmax - 1 - sn) : sn;
                int tn = min(max(trn, 0), Lmax - 1);
#pragma unroll
                for (int gate = 0; gate < 3; ++gate)
                    ring[u][gate] = gbase[(size_t)tn * 1536 + loff[gate]];
            }

            // register select: reg r = gates of sample r (D-row periodicity);
            // this lane's sample is quad -> pick reg[quad]. No cross-lane ops.
            float aR = lowhalf ? (lowquad ? cr[0] : cr[1]) : (lowquad ? cr[2] : cr[3]);
            float aZ = lowhalf ? (lowquad ? cz[0] : cz[1]) : (lowquad ? cz[2] : cz[3]);
            float aN = lowhalf ? (lowquad ? cn[0] : cn[1]) : (lowquad ? cn[2] : cn[3]);

            // gate math: ONE channel (sample=quad, hidden=j) per lane
            float rg = sigmoid_f(aR + gx0);
            float zg = sigmoid_f(aZ + gx1);
            float ng = tanh_f(gx2 + rg * aN);
            float hnew = ng + zg * (h - ng);
            bool upd = (s < Lmax) && (t < len1);
            h = upd ? hnew : h;
            bf16_t h16 = (bf16_t)h;
            hn[quad * HPAD + j] = h16;            // LDS row = sample
            hb[(size_t)t * 512 + hoff] = h16;     // hist2 per-block region

            lds_barrier();   // new h visible; old buffer free
        }
    }
}

// -------- K45 (fused K4+K5), 256 threads (R11 best config): one block per
// sample. Per 16-t chunk (t < len only): scores via MFMA with M-dim = time
// (4 waves x 2 n-tiles, K=256 over h_f||h_b, N=128), then in-block softmax
// over valid t and pooled. hist2 rows at t>=len are stale/poison but FINITE
// (0xAA bf16 ~ -3e-13) and masked by t<len.
__global__ __launch_bounds__(256) void k45_pool(const bf16_t* __restrict__ hist2,
                                                const bf16_t* __restrict__ wh2o_bf,
                                                const float* __restrict__ bh2o,
                                                const float* __restrict__ uw,
                                                const int* __restrict__ lens,
                                                float* __restrict__ out) {
    int b = blockIdx.x;
    int g16 = b >> 2, bl = b & 3;
    int tid = threadIdx.x;
    int lane = tid & 63, w2 = tid >> 6;       // 4 waves
    int quad = lane >> 4, col = lane & 15;
    int len = lens[b];

    __shared__ float smax[TT][4];   // per-wave partial scores, 8 KB
    __shared__ float alpha[TT];
    __shared__ float red[256];

    const bf16_t* hf = hist2 + (size_t)g16 * TT * 512 + bl * 128;        // fwd
    const bf16_t* hbk = hist2 + (size_t)(16 + g16) * TT * 512 + bl * 128; // bwd

    // this wave's 2 n-tiles (N=128 total over 4 waves)
    int n0 = (w2 * 2 + 0) * 16 + col;
    int n1 = (w2 * 2 + 1) * 16 + col;
    float bias0 = bh2o[n0], u0 = uw[n0];
    float bias1 = bh2o[n1], u1 = uw[n1];

    int nch = (len + 15) >> 4;
    for (int ch = 0; ch < nch; ++ch) {
        int t0 = ch * 16;
        int t = t0 + col;                 // A row m = t offset (t <= 511)
        bf16x8 a[8];
#pragma unroll
        for (int kc = 0; kc < 4; ++kc) {
            a[kc]     = ldb8(hf  + (size_t)t * 512 + kc * 32 + quad * 8);
            a[kc + 4] = ldb8(hbk + (size_t)t * 512 + kc * 32 + quad * 8);
        }
        float p4[4] = {0.f, 0.f, 0.f, 0.f};
#pragma unroll
        for (int tl = 0; tl < 2; ++tl) {
            int n = tl ? n1 : n0;
            float bias = tl ? bias1 : bias0;
            float u = tl ? u1 : u0;
            floatx4 acc = {0.f, 0.f, 0.f, 0.f};
#pragma unroll
            for (int kc = 0; kc < 8; ++kc) {
                bf16x8 bw = ldb8(wh2o_bf + (size_t)n * 256 + kc * 32 + quad * 8);
                acc = __builtin_amdgcn_mfma_f32_16x16x32_bf16(a[kc], bw, acc, 0, 0, 0);
            }
#pragma unroll
            for (int r = 0; r < 4; ++r)
                p4[r] += tanh_f(acc[r] + bias) * u;
        }
        // reduce over the 16 cols of this quad group (D rows = t's)
#pragma unroll
        for (int m = 1; m < 16; m <<= 1)
#pragma unroll
            for (int r = 0; r < 4; ++r)
                p4[r] += __shfl_xor(p4[r], m, 64);
        if (col == 0) {
#pragma unroll
            for (int r = 0; r < 4; ++r)
                smax[t0 + quad * 4 + r][w2] = p4[r];
        }
    }
    __syncthreads();

    // softmax over valid t
    float mx = -1e30f;
    for (int t = tid; t < TT; t += 256) {
        float s = -1e30f;
        if (t < len) s = smax[t][0] + smax[t][1] + smax[t][2] + smax[t][3];
        alpha[t] = s;
        mx = fmaxf(mx, s);
    }
    red[tid] = mx;
    __syncthreads();
    for (int s = 128; s > 0; s >>= 1) {
        if (tid < s) red[tid] = fmaxf(red[tid], red[tid + s]);
        __syncthreads();
    }
    mx = red[0];
    __syncthreads();
    float sum = 0.f;
    for (int t = tid; t < TT; t += 256) {
        float e = (t < len) ? __expf(alpha[t] - mx) : 0.f;
        alpha[t] = e;
        sum += e;
    }
    red[tid] = sum;
    __syncthreads();
    for (int s = 128; s > 0; s >>= 1) {
        if (tid < s) red[tid] += red[tid + s];
        __syncthreads();
    }
    float inv = fast_rcp(red[0]);
    __syncthreads();

    // pooled: 256 threads = 256 output channels
    int c = tid;
    int dir = c >> 7;
    int j = c & 127;
    const bf16_t* hbase = (dir ? hbk : hf) + j;
    float acc = 0.f;
    int t = 0;
    for (; t + 4 <= len; t += 4) {
        acc += alpha[t + 0] * (float)hbase[(size_t)(t + 0) * 512];
        acc += alpha[t + 1] * (float)hbase[(size_t)(t + 1) * 512];
        acc += alpha[t + 2] * (float)hbase[(size_t)(t + 2) * 512];
        acc += alpha[t + 3] * (float)hbase[(size_t)(t + 3) * 512];
    }
    for (; t < len; ++t) acc += alpha[t] * (float)hbase[(size_t)t * 512];

    out[(size_t)b * 256 + c] = acc * inv;
}

extern "C" void kernel_launch(void* const* d_in, const int* in_sizes, int n_in,
                              void* d_out, int out_size, void* d_ws, size_t ws_size,
                              hipStream_t stream) {
    const int* X       = (const int*)d_in[0];
    const int* lens    = (const int*)d_in[1];
    const float* emb   = (const float*)d_in[3];
    const float* We2i  = (const float*)d_in[4];
    const float* be2i  = (const float*)d_in[5];
    const float* Wihf  = (const float*)d_in[6];
    const float* Whhf  = (const float*)d_in[7];
    const float* bihf  = (const float*)d_in[8];
    const float* bhhf  = (const float*)d_in[9];
    const float* Wihb  = (const float*)d_in[10];
    const float* Whhb  = (const float*)d_in[11];
    const float* bihb  = (const float*)d_in[12];
    const float* bhhb  = (const float*)d_in[13];
    const float* Wh2o  = (const float*)d_in[14];
    const float* bh2o  = (const float*)d_in[15];
    const float* uw    = (const float*)d_in[16];

    char* ws = (char*)d_ws;
    size_t off = 0;
    bf16_t* we_bf = (bf16_t*)(ws + off);   off += (size_t)HH * EE * 2;          // 32 KB
    bf16_t* wih_bf = (bf16_t*)(ws + off);  off += (size_t)2 * 384 * HH * 2;     // 192 KB
    bf16_t* whh_bf = (bf16_t*)(ws + off);  off += (size_t)2 * 384 * HH * 2;     // 192 KB
    bf16_t* wh2o_bf = (bf16_t*)(ws + off); off += (size_t)OO * 256 * 2;         // 64 KB
    float* gxbias = (float*)(ws + off);    off += 768 * 4;                      // 3 KB
    off = (off + 255) & ~(size_t)255;
    bf16_t* gx3 = (bf16_t*)(ws + off);     off += (size_t)32 * TT * 384 * 4 * 2; // 50.3 MB
    bf16_t* hist2 = (bf16_t*)(ws + off);   off += (size_t)32 * TT * 4 * 128 * 2; // 16.8 MB

    float* out = (float*)d_out;

    k0_conv<<<dim3(256), dim3(256), 0, stream>>>(We2i, Wihf, Wihb, Whhf, Whhb,
                                                 Wh2o, bihf, bhhf, bihb, bhhb,
                                                 we_bf, wih_bf, whh_bf, wh2o_bf, gxbias);
    k12_gx<<<dim3(TT), dim3(256), 0, stream>>>(X, emb, we_bf, be2i, wih_bf, gxbias, lens, gx3);
    k3_gru<<<dim3(16, 2), dim3(512), 0, stream>>>(gx3, whh_bf, bhhf, bhhb, lens, hist2);
    k45_pool<<<dim3(BB), dim3(256), 0, stream>>>(hist2, wh2o_bf, bh2o, uw, lens, out);
}